// Round 1
// baseline (4590.521 us; speedup 1.0000x reference)
//
#include <hip/hip_runtime.h>
#include <cstdint>

// ---------------------------------------------------------------------------
// SimpleViT forward on gfx950. bf16 MFMA for all GEMMs, f32 residual stream.
// B=32, T=196, D=768, NH=12, HD=64, L=12, MLP=3072, NC=1000.
// ---------------------------------------------------------------------------

typedef __bf16 bf16_t;
typedef __bf16 bf16x8 __attribute__((ext_vector_type(8)));
typedef float  f32x4  __attribute__((ext_vector_type(4)));

#define NLAYER 12

// async global->LDS, 16B per lane (HW: wave-uniform base + lane*16)
__device__ __forceinline__ void g2lds16(const void* g, void* l) {
  __builtin_amdgcn_global_load_lds(
      (const __attribute__((address_space(1))) void*)g,
      (__attribute__((address_space(3))) void*)l, 16, 0, 0);
}

// ---------------------------------------------------------------------------
// Weight transpose + f32->bf16: in [R][C] f32 -> out [C][R] bf16 (batched).
// out base offset = (bi/innerN)*outOuter + (bi%innerN)*outInner
// ---------------------------------------------------------------------------
__global__ __launch_bounds__(256) void tcvt(
    const float* __restrict__ in, bf16_t* __restrict__ out,
    int R, int C, long inStride, long outOuter, long outInner, int innerN)
{
  int bi = blockIdx.z;
  in  += (long)bi * inStride;
  out += (long)(bi / innerN) * outOuter + (long)(bi % innerN) * outInner;
  __shared__ float t[32][33];
  int c0 = blockIdx.x * 32, r0 = blockIdx.y * 32;
  int tx = threadIdx.x, ty = threadIdx.y;
  #pragma unroll
  for (int i = ty; i < 32; i += 8) {
    int r = r0 + i, c = c0 + tx;
    if (r < R && c < C) t[i][tx] = in[(long)r * C + c];
  }
  __syncthreads();
  #pragma unroll
  for (int i = ty; i < 32; i += 8) {
    int c = c0 + i, r = r0 + tx;
    if (r < R && c < C) out[(long)c * R + r] = (bf16_t)t[tx][i];
  }
}

// ---------------------------------------------------------------------------
// Patchify: x[32,3,224,224] f32 -> patches[6272,768] bf16
// pd = (p1*16+p2)*3 + c ; token t = gh*14+gw
// ---------------------------------------------------------------------------
__global__ __launch_bounds__(256) void patchify(
    const float* __restrict__ x, bf16_t* __restrict__ patches)
{
  int idx = blockIdx.x * 256 + threadIdx.x;      // 0 .. 6272*768-1
  int bt = idx / 768, pd = idx % 768;
  int b = bt / 196, t = bt % 196;
  int gh = t / 14, gw = t % 14;
  int p1 = pd / 48, rem = pd % 48;
  int p2 = rem / 3, c = rem % 3;
  float v = x[(((long)(b * 3 + c) * 224) + gh * 16 + p1) * 224 + gw * 16 + p2];
  patches[idx] = (bf16_t)v;
}

// ---------------------------------------------------------------------------
// posemb_sincos_2d -> f32 [196][768]
// ---------------------------------------------------------------------------
__global__ __launch_bounds__(256) void posembk(float* __restrict__ pos)
{
  int idx = blockIdx.x * 256 + threadIdx.x;      // 0 .. 196*768-1
  int t = idx / 768, d = idx % 768;
  int gh = t / 14, gw = t % 14;
  int quadrant = d / 192, i = d % 192;
  float omega = powf(10000.0f, -(float)i / 191.0f);
  float arg = (quadrant < 2 ? (float)gw : (float)gh) * omega;
  pos[idx] = ((quadrant & 1) == 0) ? sinf(arg) : cosf(arg);
}

// ---------------------------------------------------------------------------
// LayerNorm: one wave per row. h f32[6272][768] -> xn bf16 (with g,b).
// ---------------------------------------------------------------------------
__global__ __launch_bounds__(64) void layernorm(
    const float* __restrict__ h, const float* __restrict__ g,
    const float* __restrict__ bb, bf16_t* __restrict__ xn)
{
  int row = blockIdx.x, lane = threadIdx.x;
  const float4* hr = (const float4*)(h + (long)row * 768);
  float4 v[3];
  float s = 0.f, s2 = 0.f;
  #pragma unroll
  for (int i = 0; i < 3; ++i) {
    v[i] = hr[lane + 64 * i];
    s  += v[i].x + v[i].y + v[i].z + v[i].w;
    s2 += v[i].x * v[i].x + v[i].y * v[i].y + v[i].z * v[i].z + v[i].w * v[i].w;
  }
  #pragma unroll
  for (int d = 1; d < 64; d <<= 1) {
    s  += __shfl_xor(s, d, 64);
    s2 += __shfl_xor(s2, d, 64);
  }
  float mu = s * (1.0f / 768.0f);
  float var = s2 * (1.0f / 768.0f) - mu * mu;
  float rs = rsqrtf(var + 1e-5f);
  uint2* outv = (uint2*)(xn + (long)row * 768);
  const float4* gv = (const float4*)g;
  const float4* bv = (const float4*)bb;
  #pragma unroll
  for (int i = 0; i < 3; ++i) {
    int c4 = lane + 64 * i;
    float4 gg = gv[c4], b4 = bv[c4];
    union { bf16_t q[4]; uint2 u; } pk;
    pk.q[0] = (bf16_t)((v[i].x - mu) * rs * gg.x + b4.x);
    pk.q[1] = (bf16_t)((v[i].y - mu) * rs * gg.y + b4.y);
    pk.q[2] = (bf16_t)((v[i].z - mu) * rs * gg.z + b4.z);
    pk.q[3] = (bf16_t)((v[i].w - mu) * rs * gg.w + b4.w);
    outv[c4] = pk.u;
  }
}

// ---------------------------------------------------------------------------
// Main GEMM: C[M,N] = A[M,K] * Bt[N,K]^T.  128x128 tile, BK=32, 4 waves.
// EPI: 0 = bf16 store (QKV)          bout, ldc
//      1 = f32 store + bias + posemb (embed)  fout=h
//      2 = f32 accumulate += acc + bias (residual: Wo, MLP2)
//      3 = gelu(acc+bias) -> bf16    (MLP1)
//      4 = f32 store, masked          (head)
// ---------------------------------------------------------------------------
template <int EPI>
__global__ __launch_bounds__(256) void gemm_bt(
    const bf16_t* __restrict__ A, const bf16_t* __restrict__ Bt,
    int K, int ldc, int Mstore, int Nstore,
    const float* __restrict__ bias, const float* __restrict__ extra,
    float* __restrict__ fout, bf16_t* __restrict__ bout)
{
  __shared__ __align__(16) bf16_t As[128 * 32];
  __shared__ __align__(16) bf16_t Bs[128 * 32];
  int tid = threadIdx.x;
  int wave = tid >> 6, lane = tid & 63, quad = lane >> 4, l16 = lane & 15;
  int wm = wave >> 1, wn = wave & 1;
  int bm = blockIdx.y, bn = blockIdx.x;
  const bf16_t* Ab = A + (long)bm * 128 * K;
  const bf16_t* Bb = Bt + (long)bn * 128 * K;

  f32x4 zero = {0.f, 0.f, 0.f, 0.f};
  f32x4 acc[4][4];
  #pragma unroll
  for (int i = 0; i < 4; ++i)
    #pragma unroll
    for (int j = 0; j < 4; ++j) acc[i][j] = zero;

  int f0 = tid * 16;            // byte id in 4KB staging round
  int row0 = f0 >> 6;           // 0..63 (64B per 32-elem row)
  int ke0 = (f0 & 63) >> 1;     // element offset within row: 0,8,16,24

  for (int kt = 0; kt < K; kt += 32) {
    __syncthreads();  // everyone done reading previous tile
    g2lds16(Ab + (long)row0 * K + kt + ke0,        (char*)As + f0);
    g2lds16(Ab + (long)(row0 + 64) * K + kt + ke0, (char*)As + f0 + 4096);
    g2lds16(Bb + (long)row0 * K + kt + ke0,        (char*)Bs + f0);
    g2lds16(Bb + (long)(row0 + 64) * K + kt + ke0, (char*)Bs + f0 + 4096);
    __syncthreads();  // staged data visible

    bf16x8 af[4], bfr[4];
    #pragma unroll
    for (int i = 0; i < 4; ++i)
      af[i] = *(const bf16x8*)(As + (wm * 64 + i * 16 + l16) * 32 + quad * 8);
    #pragma unroll
    for (int j = 0; j < 4; ++j)
      bfr[j] = *(const bf16x8*)(Bs + (wn * 64 + j * 16 + l16) * 32 + quad * 8);
    #pragma unroll
    for (int i = 0; i < 4; ++i)
      #pragma unroll
      for (int j = 0; j < 4; ++j)
        acc[i][j] = __builtin_amdgcn_mfma_f32_16x16x32_bf16(af[i], bfr[j], acc[i][j], 0, 0, 0);
  }

  int m0 = bm * 128 + wm * 64, n0 = bn * 128 + wn * 64;
  #pragma unroll
  for (int i = 0; i < 4; ++i)
    #pragma unroll
    for (int j = 0; j < 4; ++j)
      #pragma unroll
      for (int r = 0; r < 4; ++r) {
        int row = m0 + i * 16 + quad * 4 + r;
        int col = n0 + j * 16 + l16;
        if (row >= Mstore || col >= Nstore) continue;
        float v = acc[i][j][r];
        if (EPI == 0) {
          bout[(long)row * ldc + col] = (bf16_t)v;
        } else if (EPI == 1) {
          fout[(long)row * ldc + col] = v + bias[col] + extra[(row % 196) * 768 + col];
        } else if (EPI == 2) {
          fout[(long)row * ldc + col] += v + bias[col];
        } else if (EPI == 3) {
          float xg = v + bias[col];
          bout[(long)row * ldc + col] =
              (bf16_t)(0.5f * xg * (1.0f + erff(xg * 0.70710678118654752f)));
        } else {
          fout[(long)row * ldc + col] = v;
        }
      }
}

// ---------------------------------------------------------------------------
// V transpose: qkv v-part [bt][1536 + h*64 + e] -> Vt[bh][64][224] bf16,
// cols s>=196 zero-filled (so padded-K contributions vanish in PV).
// grid (2, 7, 384), block (32,8)
// ---------------------------------------------------------------------------
__global__ __launch_bounds__(256) void vtrans(
    const bf16_t* __restrict__ qkv, bf16_t* __restrict__ Vt)
{
  int bh = blockIdx.z, b = bh / 12, h = bh % 12;
  __shared__ bf16_t t[32][33];
  int e0 = blockIdx.x * 32, s0 = blockIdx.y * 32;
  int tx = threadIdx.x, ty = threadIdx.y;
  #pragma unroll
  for (int i = ty; i < 32; i += 8) {
    int s = s0 + i;
    bf16_t v = (bf16_t)0.0f;
    if (s < 196) v = qkv[(long)(b * 196 + s) * 2304 + 1536 + h * 64 + e0 + tx];
    t[i][tx] = v;
  }
  __syncthreads();
  #pragma unroll
  for (int i = ty; i < 32; i += 8) {
    int e = e0 + i, s = s0 + tx;
    if (s < 224) Vt[(long)bh * 64 * 224 + (long)e * 224 + s] = t[tx][i];
  }
}

// ---------------------------------------------------------------------------
// Scores + softmax: one wave per (mtile, b, h). S[16,208] = Q_tile @ K^T,
// scale 0.125, masked softmax over cols (valid < 196), write P bf16.
// P layout: [bh][208 rows][224 cols] (cols 208..223 left as-is; Vt is 0 there)
// grid (13, 384), block 64
// ---------------------------------------------------------------------------
__global__ __launch_bounds__(64) void attn_scores(
    const bf16_t* __restrict__ qkv, bf16_t* __restrict__ P)
{
  int mt = blockIdx.x, bh = blockIdx.y;
  int b = bh / 12, h = bh % 12;
  int lane = threadIdx.x, quad = lane >> 4, l16 = lane & 15;

  f32x4 zero = {0.f, 0.f, 0.f, 0.f};
  f32x4 acc[13];
  #pragma unroll
  for (int nt = 0; nt < 13; ++nt) acc[nt] = zero;

  long qoff = (long)(b * 196 + mt * 16 + l16) * 2304 + h * 64;
  #pragma unroll
  for (int kk = 0; kk < 2; ++kk) {
    bf16x8 a = *(const bf16x8*)(qkv + qoff + kk * 32 + quad * 8);
    #pragma unroll
    for (int nt = 0; nt < 13; ++nt) {
      long koff = (long)(b * 196 + nt * 16 + l16) * 2304 + 768 + h * 64 + kk * 32 + quad * 8;
      bf16x8 bb = *(const bf16x8*)(qkv + koff);
      acc[nt] = __builtin_amdgcn_mfma_f32_16x16x32_bf16(a, bb, acc[nt], 0, 0, 0);
    }
  }

  float p[13][4];
  #pragma unroll
  for (int nt = 0; nt < 13; ++nt)
    #pragma unroll
    for (int r = 0; r < 4; ++r) {
      float v = acc[nt][r] * 0.125f;
      if (nt == 12 && l16 >= 4) v = -1e30f;   // cols >= 196 masked
      p[nt][r] = v;
    }

  #pragma unroll
  for (int r = 0; r < 4; ++r) {
    float mx = -1e30f;
    #pragma unroll
    for (int nt = 0; nt < 13; ++nt) mx = fmaxf(mx, p[nt][r]);
    #pragma unroll
    for (int d = 1; d < 16; d <<= 1) mx = fmaxf(mx, __shfl_xor(mx, d, 64));
    float sm = 0.f;
    #pragma unroll
    for (int nt = 0; nt < 13; ++nt) {
      float e = expf(p[nt][r] - mx);
      p[nt][r] = e;
      sm += e;
    }
    #pragma unroll
    for (int d = 1; d < 16; d <<= 1) sm += __shfl_xor(sm, d, 64);
    float inv = 1.0f / sm;
    #pragma unroll
    for (int nt = 0; nt < 13; ++nt) p[nt][r] *= inv;
  }

  long base = (long)bh * 208 * 224 + (long)(mt * 16 + quad * 4) * 224 + l16;
  #pragma unroll
  for (int nt = 0; nt < 13; ++nt)
    #pragma unroll
    for (int r = 0; r < 4; ++r)
      P[base + (long)r * 224 + nt * 16] = (bf16_t)p[nt][r];
}

// ---------------------------------------------------------------------------
// PV: att_tile[16,64] = P[16,224] @ V[224,64]  (Vt holds V^T, zero-padded)
// writes att[bt][768] (heads concatenated). grid (13, 384), block 64
// ---------------------------------------------------------------------------
__global__ __launch_bounds__(64) void attn_pv(
    const bf16_t* __restrict__ P, const bf16_t* __restrict__ Vt,
    bf16_t* __restrict__ att)
{
  int mt = blockIdx.x, bh = blockIdx.y;
  int b = bh / 12, h = bh % 12;
  int lane = threadIdx.x, quad = lane >> 4, l16 = lane & 15;

  f32x4 zero = {0.f, 0.f, 0.f, 0.f};
  f32x4 acc[4];
  #pragma unroll
  for (int nt = 0; nt < 4; ++nt) acc[nt] = zero;

  const bf16_t* Prow = P + (long)bh * 208 * 224 + (long)(mt * 16 + l16) * 224;
  const bf16_t* Vb = Vt + (long)bh * 64 * 224;
  #pragma unroll
  for (int ks = 0; ks < 7; ++ks) {
    bf16x8 a = *(const bf16x8*)(Prow + ks * 32 + quad * 8);
    #pragma unroll
    for (int nt = 0; nt < 4; ++nt) {
      bf16x8 bb = *(const bf16x8*)(Vb + (long)(nt * 16 + l16) * 224 + ks * 32 + quad * 8);
      acc[nt] = __builtin_amdgcn_mfma_f32_16x16x32_bf16(a, bb, acc[nt], 0, 0, 0);
    }
  }

  #pragma unroll
  for (int nt = 0; nt < 4; ++nt)
    #pragma unroll
    for (int r = 0; r < 4; ++r) {
      int t = mt * 16 + quad * 4 + r;
      if (t < 196)
        att[(long)(b * 196 + t) * 768 + h * 64 + nt * 16 + l16] = (bf16_t)acc[nt][r];
    }
}

// ---------------------------------------------------------------------------
// Mean pool over tokens: h f32 [6272][768] -> hm bf16 [128][768] (rows 0..31)
// grid (32, 3), block 256
// ---------------------------------------------------------------------------
__global__ __launch_bounds__(256) void meanpool(
    const float* __restrict__ h, bf16_t* __restrict__ hm)
{
  int d = blockIdx.y * 256 + threadIdx.x;
  int b = blockIdx.x;
  float s = 0.f;
  for (int t = 0; t < 196; ++t) s += h[(long)(b * 196 + t) * 768 + d];
  hm[b * 768 + d] = (bf16_t)(s * (1.0f / 196.0f));
}

// ---------------------------------------------------------------------------
// Host launch
// ---------------------------------------------------------------------------
extern "C" void kernel_launch(void* const* d_in, const int* in_sizes, int n_in,
                              void* d_out, int out_size, void* d_ws, size_t ws_size,
                              hipStream_t stream)
{
  const float* x       = (const float*)d_in[0];
  const float* embed_W = (const float*)d_in[1];
  const float* embed_b = (const float*)d_in[2];
  const float* Wq      = (const float*)d_in[3];
  const float* Wk      = (const float*)d_in[4];
  const float* Wv      = (const float*)d_in[5];
  const float* Wo      = (const float*)d_in[6];
  const float* bo      = (const float*)d_in[7];
  const float* ln1_g   = (const float*)d_in[8];
  const float* ln1_b   = (const float*)d_in[9];
  const float* ln2_g   = (const float*)d_in[10];
  const float* ln2_b   = (const float*)d_in[11];
  const float* W1      = (const float*)d_in[12];
  const float* b1      = (const float*)d_in[13];
  const float* W2      = (const float*)d_in[14];
  const float* b2      = (const float*)d_in[15];
  const float* head_W  = (const float*)d_in[16];

  // ---- workspace carve (all recomputed every call; ~300 MB) ----
  char* p = (char*)d_ws;
  auto carve = [&](size_t bytes) {
    char* r = p;
    p += (bytes + 255) & ~(size_t)255;
    return r;
  };
  bf16_t* embed_Wt = (bf16_t*)carve(589824ull * 2);           // [768][768]
  bf16_t* qkvT     = (bf16_t*)carve(21233664ull * 2);         // 12 x [2304][768]
  bf16_t* WoT      = (bf16_t*)carve(7077888ull * 2);          // 12 x [768][768]
  bf16_t* W1T      = (bf16_t*)carve(28311552ull * 2);         // 12 x [3072][768]
  bf16_t* W2T      = (bf16_t*)carve(28311552ull * 2);         // 12 x [768][3072]
  bf16_t* headWt   = (bf16_t*)carve(786432ull * 2);           // [1024][768] (rows>=1000 junk)
  float*  pos      = (float*)carve(150528ull * 4);            // [196][768]
  bf16_t* patches  = (bf16_t*)carve(4816896ull * 2);          // [6272][768]
  float*  h        = (float*)carve(4816896ull * 4);           // [6272][768]
  bf16_t* xn       = (bf16_t*)carve(4816896ull * 2);          // [6272][768]
  bf16_t* qkv      = (bf16_t*)carve(14487552ull * 2);         // [6288][2304] (+slack rows)
  bf16_t* Vt       = (bf16_t*)carve(5505024ull * 2);          // [384][64][224]
  bf16_t* Pb       = (bf16_t*)carve(38535168ull);             // union: P [384][208][224] / hmlp [6272][3072]
  bf16_t* att      = (bf16_t*)carve(4816896ull * 2);          // [6272][768]
  bf16_t* hm       = (bf16_t*)carve(98304ull * 2);            // [128][768] (rows>=32 junk)
  bf16_t* hmlp = Pb;                                          // alias (no lifetime overlap)
  (void)ws_size; (void)n_in; (void)in_sizes; (void)out_size;

  dim3 tb32(32, 8);

  // ---- weight prep: f32 -> bf16, B^T layout ----
  tcvt<<<dim3(24, 24, 1),   tb32, 0, stream>>>(embed_W, embed_Wt, 768, 768, 0, 0, 0, 1);
  tcvt<<<dim3(24, 24, 12),  tb32, 0, stream>>>(Wo, WoT, 768, 768, 589824, 589824, 0, 1);
  tcvt<<<dim3(2, 24, 144),  tb32, 0, stream>>>(Wq, qkvT,           768, 64, 49152, 1769472, 49152, 12);
  tcvt<<<dim3(2, 24, 144),  tb32, 0, stream>>>(Wk, qkvT + 589824,  768, 64, 49152, 1769472, 49152, 12);
  tcvt<<<dim3(2, 24, 144),  tb32, 0, stream>>>(Wv, qkvT + 1179648, 768, 64, 49152, 1769472, 49152, 12);
  tcvt<<<dim3(96, 24, 12),  tb32, 0, stream>>>(W1, W1T, 768, 3072, 2359296, 2359296, 0, 1);
  tcvt<<<dim3(24, 96, 12),  tb32, 0, stream>>>(W2, W2T, 3072, 768, 2359296, 2359296, 0, 1);
  tcvt<<<dim3(32, 24, 1),   tb32, 0, stream>>>(head_W, headWt, 768, 1000, 0, 0, 0, 1);

  // ---- patchify + positional embedding ----
  patchify<<<18816, 256, 0, stream>>>(x, patches);
  posembk<<<588, 256, 0, stream>>>(pos);

  // ---- patch embed GEMM: h = patches @ embed_W + b + posemb ----
  gemm_bt<1><<<dim3(6, 49), 256, 0, stream>>>(
      patches, embed_Wt, 768, 768, 6272, 768, embed_b, pos, h, nullptr);

  for (int l = 0; l < NLAYER; ++l) {
    layernorm<<<6272, 64, 0, stream>>>(h, ln1_g + l * 768, ln1_b + l * 768, xn);
    gemm_bt<0><<<dim3(18, 49), 256, 0, stream>>>(
        xn, qkvT + (long)l * 1769472, 768, 2304, 6272, 2304,
        nullptr, nullptr, nullptr, qkv);
    vtrans<<<dim3(2, 7, 384), tb32, 0, stream>>>(qkv, Vt);
    attn_scores<<<dim3(13, 384), 64, 0, stream>>>(qkv, Pb);
    attn_pv<<<dim3(13, 384), 64, 0, stream>>>(Pb, Vt, att);
    gemm_bt<2><<<dim3(6, 49), 256, 0, stream>>>(
        att, WoT + (long)l * 589824, 768, 768, 6272, 768,
        bo + l * 768, nullptr, h, nullptr);
    layernorm<<<6272, 64, 0, stream>>>(h, ln2_g + l * 768, ln2_b + l * 768, xn);
    gemm_bt<3><<<dim3(24, 49), 256, 0, stream>>>(
        xn, W1T + (long)l * 2359296, 768, 3072, 6272, 3072,
        b1 + l * 3072, nullptr, nullptr, hmlp);
    gemm_bt<2><<<dim3(6, 49), 256, 0, stream>>>(
        hmlp, W2T + (long)l * 2359296, 3072, 768, 6272, 768,
        b2 + l * 768, nullptr, h, nullptr);
  }

  meanpool<<<dim3(32, 3), 256, 0, stream>>>(h, hm);
  gemm_bt<4><<<dim3(8, 1), 256, 0, stream>>>(
      hm, headWt, 768, 1000, 32, 1000, nullptr, nullptr, (float*)d_out, nullptr);
}